// Round 1
// baseline (377.821 us; speedup 1.0000x reference)
//
#include <hip/hip_runtime.h>
#include <stdint.h>

typedef __attribute__((ext_vector_type(8))) short bf16x8;
typedef __attribute__((ext_vector_type(4))) float f32x4;

#define MFMA16(A, B, C) __builtin_amdgcn_mfma_f32_16x16x32_bf16(A, B, C, 0, 0, 0)

static __device__ __forceinline__ unsigned short f2bf(float f) {
  uint32_t u = __float_as_uint(f);
  u = (u + 0x7fffu + ((u >> 16) & 1u)) >> 16;
  return (unsigned short)u;
}

static __device__ __forceinline__ bf16x8 pack8(float4 a, float4 b) {
  bf16x8 r;
  r[0] = (short)f2bf(a.x); r[1] = (short)f2bf(a.y);
  r[2] = (short)f2bf(a.z); r[3] = (short)f2bf(a.w);
  r[4] = (short)f2bf(b.x); r[5] = (short)f2bf(b.y);
  r[6] = (short)f2bf(b.z); r[7] = (short)f2bf(b.w);
  return r;
}

// ---------------- K0: weight prep (f32 -> bf16, Wsr transposed to [o][s*128+c]) ----------
#define TOT_PREP (16384 + 16384 + 32768 + 1048576)
__global__ void prep_kernel(const float* __restrict__ Wq, const float* __restrict__ Wkv,
                            const float* __restrict__ Wp, const float* __restrict__ Wsr,
                            unsigned short* __restrict__ Wq_bf, unsigned short* __restrict__ Wkv_bf,
                            unsigned short* __restrict__ Wp_bf, unsigned short* __restrict__ Wsrt_bf) {
  int idx = blockIdx.x * 256 + threadIdx.x;
  if (idx >= TOT_PREP) return;
  if (idx < 16384) { Wq_bf[idx] = f2bf(Wq[idx]); return; }
  idx -= 16384;
  if (idx < 16384) { Wp_bf[idx] = f2bf(Wp[idx]); return; }
  idx -= 16384;
  if (idx < 32768) { Wkv_bf[idx] = f2bf(Wkv[idx]); return; }
  idx -= 32768;
  // Wsr: [o][c][kh][kw] -> Wsrt: [o][s*128+c], s = kh*8+kw
  int o = idx >> 13, r13 = idx & 8191, s = r13 >> 7, c = r13 & 127;
  Wsrt_bf[idx] = f2bf(Wsr[(o << 13) + (c << 6) + s]);
}

// ---------------- K1: strided 8x8 conv (as patch-GEMM) + bias + LayerNorm + KV proj ------
// grid: 128 blocks, each handles 16 patches (rows). 4 waves split K=8192 four ways.
__global__ __launch_bounds__(256, 2) void conv_ln_kv_kernel(
    const float* __restrict__ x, const unsigned short* __restrict__ Wsrt_bf,
    const float* __restrict__ bsr, const float* __restrict__ gamma, const float* __restrict__ beta,
    const unsigned short* __restrict__ Wkv_bf, const float* __restrict__ bkv,
    unsigned short* __restrict__ K_bf, unsigned short* __restrict__ Vt_bf) {
  const int tid = threadIdx.x;
  const int wave = tid >> 6, l = tid & 63, lg = l >> 4, lr = l & 15;
  const int blk = blockIdx.x;

  __shared__ float red[4][16][128];          // 32 KB split-K partials
  __shared__ unsigned short lns[16][136];    // LN output, bf16, padded row stride

  const f32x4 zr = {0.f, 0.f, 0.f, 0.f};
  f32x4 acc[8];
#pragma unroll
  for (int ct = 0; ct < 8; ++ct) acc[ct] = zr;

  const int p = blk * 16 + lr;               // this lane's patch (A-frag row)
  const int b = p >> 8, ii = (p >> 4) & 15, jj = p & 15;

  for (int kt = 0; kt < 64; ++kt) {
    const int k = wave * 2048 + kt * 32;     // k = s*128 + c
    const int s = k >> 7, c0 = k & 127;
    const int kh = s >> 3, kw = s & 7;
    const int y = ii * 8 + kh, xx = jj * 8 + kw;
    const float4* xp = (const float4*)(x + ((size_t)(b * 16384 + y * 128 + xx)) * 128 + c0 + lg * 8);
    bf16x8 af = pack8(xp[0], xp[1]);
    const unsigned short* wb = Wsrt_bf + k + lg * 8;
#pragma unroll
    for (int ct = 0; ct < 8; ++ct) {
      bf16x8 bfr = *(const bf16x8*)(wb + (ct * 16 + lr) * 8192);
      acc[ct] = MFMA16(af, bfr, acc[ct]);
    }
  }

  // split-K reduce via LDS
#pragma unroll
  for (int ct = 0; ct < 8; ++ct)
#pragma unroll
    for (int r = 0; r < 4; ++r)
      red[wave][lg * 4 + r][ct * 16 + lr] = acc[ct][r];
  __syncthreads();

#pragma unroll
  for (int rr = 0; rr < 8; ++rr) {
    int idx = rr * 256 + tid;
    int row = idx >> 7, c = idx & 127;
    float v = red[0][row][c] + red[1][row][c] + red[2][row][c] + red[3][row][c] + bsr[c];
    red[0][row][c] = v;
  }
  __syncthreads();

  // LayerNorm over c=128 per row; 16 threads per row
  {
    const int row = tid >> 4, c0 = (tid & 15) * 8;
    float vals[8];
    float s1 = 0.f, s2 = 0.f;
#pragma unroll
    for (int cc = 0; cc < 8; ++cc) {
      float v = red[0][row][c0 + cc];
      vals[cc] = v; s1 += v; s2 += v * v;
    }
#pragma unroll
    for (int msk = 1; msk < 16; msk <<= 1) { s1 += __shfl_xor(s1, msk); s2 += __shfl_xor(s2, msk); }
    float mean = s1 * (1.f / 128.f);
    float var = s2 * (1.f / 128.f) - mean * mean;
    float rstd = rsqrtf(var + 1e-5f);
#pragma unroll
    for (int cc = 0; cc < 8; ++cc) {
      int c = c0 + cc;
      lns[row][c] = f2bf((vals[cc] - mean) * rstd * gamma[c] + beta[c]);
    }
  }
  __syncthreads();

  // KV projection: [16 rows] x [256 o2], K=128. wave handles 4 o2-tiles.
  f32x4 kv[4];
#pragma unroll
  for (int q = 0; q < 4; ++q) kv[q] = zr;
#pragma unroll
  for (int kt = 0; kt < 4; ++kt) {
    bf16x8 af = *(const bf16x8*)(&lns[lr][kt * 32 + lg * 8]);
#pragma unroll
    for (int q = 0; q < 4; ++q) {
      bf16x8 bfr = *(const bf16x8*)(Wkv_bf + ((wave * 4 + q) * 16 + lr) * 128 + kt * 32 + lg * 8);
      kv[q] = MFMA16(af, bfr, kv[q]);
    }
  }
#pragma unroll
  for (int q = 0; q < 4; ++q)
#pragma unroll
    for (int r = 0; r < 4; ++r) {
      int o2 = (wave * 4 + q) * 16 + lr;
      int mrow = lg * 4 + r;
      int pp = blk * 16 + mrow;
      int bb = pp >> 8, mm = pp & 255;
      float val = kv[q][r] + bkv[o2];
      unsigned short hv = f2bf(val);
      if (o2 < 128) {                       // K: [b][h][m][d]
        int h = o2 >> 6, d = o2 & 63;
        K_bf[(((size_t)(bb * 2 + h)) * 256 + mm) * 64 + d] = hv;
      } else {                              // V transposed: [b][h][d][m]
        int o3 = o2 - 128, h = o3 >> 6, d = o3 & 63;
        Vt_bf[(((size_t)(bb * 2 + h)) * 64 + d) * 256 + mm] = hv;
      }
    }
}

// ---------------- K2: fused Qproj + attention + output projection ------------------------
// grid: (128 n-tiles, 8 batches), 256 threads, ~136 KB LDS (1 block/CU).
__global__ __launch_bounds__(256, 1) void attn_kernel(
    const float* __restrict__ x, const float* __restrict__ bq, const float* __restrict__ bp,
    const unsigned short* __restrict__ Wq_bf, const unsigned short* __restrict__ Wp_bf,
    const unsigned short* __restrict__ K_bf, const unsigned short* __restrict__ Vt_bf,
    float* __restrict__ out) {
  const int tid = threadIdx.x;
  const int wave = tid >> 6, l = tid & 63, lg = l >> 4, lr = l & 15;
  const int b = blockIdx.y;
  const int n0 = blockIdx.x * 128;

  __shared__ unsigned short Qs[128][136];   // 34816 B  (stride 272B: 16B-mult, 2 banks apart)
  __shared__ unsigned short Ks[256][72];    // 36864 B  (stride 144B)
  __shared__ unsigned short Vs[64][264];    // 33792 B  (stride 528B)  V^T: [d][m]
  __shared__ unsigned short Ps[4][16][264]; // 33792 B  per-wave P, reused as O-pass [64][136]

  const f32x4 zr = {0.f, 0.f, 0.f, 0.f};

  // ---- Q projection: wave w computes rows w*32..w*32+31 ----
  {
    f32x4 qa[2][8];
#pragma unroll
    for (int rt = 0; rt < 2; ++rt)
#pragma unroll
      for (int ct = 0; ct < 8; ++ct) qa[rt][ct] = zr;
#pragma unroll
    for (int kt = 0; kt < 4; ++kt) {
      bf16x8 af[2];
#pragma unroll
      for (int rt = 0; rt < 2; ++rt) {
        const float4* xp =
            (const float4*)(x + ((size_t)(b * 16384 + n0 + wave * 32 + rt * 16 + lr)) * 128 + kt * 32 + lg * 8);
        af[rt] = pack8(xp[0], xp[1]);
      }
#pragma unroll
      for (int ct = 0; ct < 8; ++ct) {
        bf16x8 bfr = *(const bf16x8*)(Wq_bf + (ct * 16 + lr) * 128 + kt * 32 + lg * 8);
        qa[0][ct] = MFMA16(af[0], bfr, qa[0][ct]);
        qa[1][ct] = MFMA16(af[1], bfr, qa[1][ct]);
      }
    }
#pragma unroll
    for (int rt = 0; rt < 2; ++rt)
#pragma unroll
      for (int ct = 0; ct < 8; ++ct)
#pragma unroll
        for (int r = 0; r < 4; ++r) {
          int row = wave * 32 + rt * 16 + lg * 4 + r;
          int col = ct * 16 + lr;
          Qs[row][col] = f2bf(qa[rt][ct][r] + bq[col]);
        }
  }
  __syncthreads();

  for (int pass = 0; pass < 2; ++pass) {
    f32x4 oacc[2][4];
#pragma unroll
    for (int h2 = 0; h2 < 2; ++h2)
#pragma unroll
      for (int dt = 0; dt < 4; ++dt) oacc[h2][dt] = zr;
    const int nb = pass * 64 + wave * 16;   // wave's 16 query rows (local)

    for (int h = 0; h < 2; ++h) {
      __syncthreads();
      // stage K_h [256][64] and V_h^T [64][256] into LDS
      {
        const unsigned short* ksrc = K_bf + ((size_t)(b * 2 + h)) * 256 * 64;
        const unsigned short* vsrc = Vt_bf + ((size_t)(b * 2 + h)) * 64 * 256;
#pragma unroll
        for (int it = 0; it < 8; ++it) {
          int idx = it * 2048 + tid * 8;
          int m = idx >> 6, d = idx & 63;
          *(int4*)(&Ks[m][d]) = *(const int4*)(ksrc + idx);
        }
#pragma unroll
        for (int it = 0; it < 8; ++it) {
          int idx = it * 2048 + tid * 8;
          int d = idx >> 8, m = idx & 255;
          *(int4*)(&Vs[d][m]) = *(const int4*)(vsrc + idx);
        }
      }
      __syncthreads();

      // S^T = mfma(K, Q): per wave [256 m][16 n]; lane owns n = nb + lr, all m.
      f32x4 sacc[16];
#pragma unroll
      for (int mt = 0; mt < 16; ++mt) sacc[mt] = zr;
#pragma unroll
      for (int d0 = 0; d0 < 64; d0 += 32) {
        bf16x8 qf = *(const bf16x8*)(&Qs[nb + lr][h * 64 + d0 + lg * 8]);
#pragma unroll
        for (int mt = 0; mt < 16; ++mt) {
          bf16x8 kf = *(const bf16x8*)(&Ks[mt * 16 + lr][d0 + lg * 8]);
          sacc[mt] = MFMA16(kf, qf, sacc[mt]);
        }
      }
      // softmax over m=256 for this lane's n; m = mt*16 + lg*4 + r
      float mx = -1e30f;
#pragma unroll
      for (int mt = 0; mt < 16; ++mt)
#pragma unroll
        for (int r = 0; r < 4; ++r) mx = fmaxf(mx, sacc[mt][r]);
      mx = fmaxf(mx, __shfl_xor(mx, 16));
      mx = fmaxf(mx, __shfl_xor(mx, 32));
      float sum = 0.f;
#pragma unroll
      for (int mt = 0; mt < 16; ++mt)
#pragma unroll
        for (int r = 0; r < 4; ++r) {
          float pv = __expf((sacc[mt][r] - mx) * 0.125f);
          sacc[mt][r] = pv; sum += pv;
        }
      sum += __shfl_xor(sum, 16);
      sum += __shfl_xor(sum, 32);
      float inv = 1.f / sum;
#pragma unroll
      for (int mt = 0; mt < 16; ++mt) {
        unsigned int w0 = (unsigned int)f2bf(sacc[mt][0] * inv) | ((unsigned int)f2bf(sacc[mt][1] * inv) << 16);
        unsigned int w1 = (unsigned int)f2bf(sacc[mt][2] * inv) | ((unsigned int)f2bf(sacc[mt][3] * inv) << 16);
        uint2 pw; pw.x = w0; pw.y = w1;
        *(uint2*)(&Ps[wave][lr][mt * 16 + lg * 4]) = pw;   // P[n_local=lr][m]
      }

      // PV: O[16 n][64 d] += P @ V_h
#pragma unroll
      for (int ki = 0; ki < 8; ++ki) {
        bf16x8 pf = *(const bf16x8*)(&Ps[wave][lr][ki * 32 + lg * 8]);
#pragma unroll
        for (int dt = 0; dt < 4; ++dt) {
          bf16x8 vf = *(const bf16x8*)(&Vs[dt * 16 + lr][ki * 32 + lg * 8]);
          oacc[h][dt] = MFMA16(pf, vf, oacc[h][dt]);
        }
      }
    }  // head

    __syncthreads();
    // write O (both heads) for these 64 rows into Ps region as [64][136] bf16
    unsigned short* Op = &Ps[0][0][0];
#pragma unroll
    for (int h = 0; h < 2; ++h)
#pragma unroll
      for (int dt = 0; dt < 4; ++dt)
#pragma unroll
        for (int r = 0; r < 4; ++r) {
          int row = wave * 16 + lg * 4 + r;
          int col = h * 64 + dt * 16 + lr;
          Op[row * 136 + col] = f2bf(oacc[h][dt][r]);
        }
    __syncthreads();

    // output projection for rows pass*64 .. pass*64+63
    f32x4 yacc[8];
#pragma unroll
    for (int ct = 0; ct < 8; ++ct) yacc[ct] = zr;
#pragma unroll
    for (int kt = 0; kt < 4; ++kt) {
      bf16x8 af = *(const bf16x8*)(&Op[(wave * 16 + lr) * 136 + kt * 32 + lg * 8]);
#pragma unroll
      for (int ct = 0; ct < 8; ++ct) {
        bf16x8 bfr = *(const bf16x8*)(Wp_bf + (ct * 16 + lr) * 128 + kt * 32 + lg * 8);
        yacc[ct] = MFMA16(af, bfr, yacc[ct]);
      }
    }
#pragma unroll
    for (int ct = 0; ct < 8; ++ct)
#pragma unroll
      for (int r = 0; r < 4; ++r) {
        int n = n0 + pass * 64 + wave * 16 + lg * 4 + r;
        int o = ct * 16 + lr;
        out[((size_t)(b * 16384 + n)) * 128 + o] = yacc[ct][r] + bp[o];
      }
  }  // pass
}

extern "C" void kernel_launch(void* const* d_in, const int* in_sizes, int n_in,
                              void* d_out, int out_size, void* d_ws, size_t ws_size,
                              hipStream_t stream) {
  const float* x = (const float*)d_in[0];
  // d_in[1], d_in[2] = h, w (constants 128, unused)
  const float* Wq = (const float*)d_in[3];
  const float* bq = (const float*)d_in[4];
  const float* Wkv = (const float*)d_in[5];
  const float* bkv = (const float*)d_in[6];
  const float* Wp = (const float*)d_in[7];
  const float* bp = (const float*)d_in[8];
  const float* Wsr = (const float*)d_in[9];
  const float* bsr = (const float*)d_in[10];
  const float* gamma = (const float*)d_in[11];
  const float* beta = (const float*)d_in[12];
  float* out = (float*)d_out;

  unsigned short* ws = (unsigned short*)d_ws;
  unsigned short* Wq_bf = ws;                 // 16384
  unsigned short* Wp_bf = ws + 16384;         // 16384
  unsigned short* Wkv_bf = ws + 32768;        // 32768
  unsigned short* Wsrt_bf = ws + 65536;       // 1048576
  unsigned short* K_bf = ws + 1114112;        // 262144  [8][2][256][64]
  unsigned short* Vt_bf = ws + 1376256;       // 262144  [8][2][64][256]

  prep_kernel<<<(TOT_PREP + 255) / 256, 256, 0, stream>>>(Wq, Wkv, Wp, Wsr, Wq_bf, Wkv_bf, Wp_bf, Wsrt_bf);
  conv_ln_kv_kernel<<<128, 256, 0, stream>>>(x, Wsrt_bf, bsr, gamma, beta, Wkv_bf, bkv, K_bf, Vt_bf);
  attn_kernel<<<dim3(128, 8), 256, 0, stream>>>(x, bq, bp, Wq_bf, Wp_bf, K_bf, Vt_bf, out);
}